// Round 14
// baseline (74.382 us; speedup 1.0000x reference)
//
#include <hip/hip_runtime.h>
#include <float.h>
#include <math.h>

typedef __attribute__((ext_vector_type(8))) short short8;
typedef __attribute__((ext_vector_type(8))) _Float16 half8;
typedef __attribute__((ext_vector_type(4))) float f32x4;

constexpr int B_N  = 8192;
constexpr int D_K  = 128;
constexpr int NCLS = 50;
constexpr int NCHK = 128;             // 64-col chunks
constexpr int NPBLK = 64;             // classsum partial blocks
constexpr float C_SCALE  = 28.853900817779268f;   // 20*log2(e), folded into A
constexpr float NEG_LOW  = -1.0e5f;
constexpr float NEG_MASK = -1.0e30f;

__device__ __forceinline__ float exp2fast(float x) { return __builtin_amdgcn_exp2f(x); }
__device__ __forceinline__ f32x4 mfma16(half8 a, half8 b, f32x4 c) {
    return __builtin_amdgcn_mfma_f32_16x16x32_f16(a, b, c, 0, 0, 0);
}
__device__ __forceinline__ void async_copy16(void* lds, const void* g) {
    __builtin_amdgcn_global_load_lds((const __attribute__((address_space(1))) unsigned int*)g,
                                     (__attribute__((address_space(3))) unsigned int*)lds,
                                     16, 0, 0);
}

// ---------------- prep: f32 -> f16 row-major; A pre-scaled by C_SCALE ----------------
__global__ void prep_kernel(const float* __restrict__ a, const float* __restrict__ b,
                            short* __restrict__ aH, short* __restrict__ bH)
{
    const int NPER = B_N * D_K / 8;
    int i = blockIdx.x * blockDim.x + threadIdx.x;
    const float* src = (i < NPER) ? a : b;
    short*       dst = (i < NPER) ? aH : bH;
    const float  sc  = (i < NPER) ? C_SCALE : 1.0f;
    int j = (i < NPER) ? i : i - NPER;
    const f32x4* sp = (const f32x4*)(src + (size_t)j * 8);
    f32x4 v0 = sp[0], v1 = sp[1];
    short8 h;
#pragma unroll
    for (int e = 0; e < 4; ++e) {
        h[e]     = __builtin_bit_cast(short, (_Float16)(sc * v0[e]));
        h[e + 4] = __builtin_bit_cast(short, (_Float16)(sc * v1[e]));
    }
    *(short8*)(dst + (size_t)j * 8) = h;
}

// ---------------- main: 128x64 tile, 48KB LDS (3 blocks/CU), merge-free epilogue ----------------
// 4 waves, wave w owns rows [w*32, w*32+32) x all 64 tile cols. Swapped mfma(b,a):
// lane's row = mf*16 + l15; its 16 cells/mf x 4 l16-groups = full 64 cols -> 2-shuffle
// combine, direct global write. ONE barrier per block.
__global__ __launch_bounds__(256)
void rowstats_kernel(const short* __restrict__ aH, const short* __restrict__ bH,
                     const int* __restrict__ labels,
                     float* __restrict__ pmx, float* __restrict__ ps)
{
    __shared__ __align__(16) char smem[49152];       // A 32KB | B 16KB

    const int bid    = blockIdx.x;
    const int colblk = bid & (NCHK - 1);             // 128 colblks; XCD-affine mod 8
    const int R0     = (bid >> 7) * 128;
    const int C0     = colblk * 64;

    const int tid = threadIdx.x;
    const int wid = tid >> 6, l = tid & 63;
    const int l15 = l & 15, l16 = l >> 4;

    // labels (latency hides under staging)
    int labA[2];
#pragma unroll
    for (int mf = 0; mf < 2; ++mf)
        labA[mf] = labels[R0 + wid * 32 + mf * 16 + l15];
    int lb[4][4];
#pragma unroll
    for (int nf = 0; nf < 4; ++nf) {
        int4 t4 = *(const int4*)(labels + C0 + nf * 16 + l16 * 4);
        lb[nf][0] = t4.x; lb[nf][1] = t4.y; lb[nf][2] = t4.z; lb[nf][3] = t4.w;
    }

    // ---- stage A (128 rows) + B (64 cols) tiles, swizzled source -> linear LDS ----
    {
        const int srow = tid >> 4, sp = tid & 15;
#pragma unroll
        for (int is = 0; is < 8; ++is) {
            int row = is * 16 + srow;
            int gs  = sp ^ (row & 7);
            async_copy16(smem + is * 4096 + (wid << 10),
                         aH + (size_t)(R0 + row) * D_K + gs * 8);
        }
#pragma unroll
        for (int is = 0; is < 4; ++is) {
            int row = is * 16 + srow;
            int gs  = sp ^ (row & 7);
            async_copy16(smem + 32768 + is * 4096 + (wid << 10),
                         bH + (size_t)(C0 + row) * D_K + gs * 8);
        }
    }
    __syncthreads();                                 // single barrier (drains vmcnt)

    // ---- K=128 sweep: 4 k-steps x 2x4 frags, swapped operands ----
    f32x4 acc[2][4];
#pragma unroll
    for (int mf = 0; mf < 2; ++mf)
#pragma unroll
        for (int nf = 0; nf < 4; ++nf) acc[mf][nf] = f32x4{0.f, 0.f, 0.f, 0.f};

    const int swz = l15 & 7;
#pragma unroll
    for (int ks = 0; ks < 4; ++ks) {
        const int g = (ks * 4 + l16) ^ swz;
        half8 af[2], bf[4];
#pragma unroll
        for (int mf = 0; mf < 2; ++mf) {
            int row = wid * 32 + mf * 16 + l15;
            af[mf] = *(const half8*)(smem + row * 256 + g * 16);
        }
#pragma unroll
        for (int nf = 0; nf < 4; ++nf) {
            int brow = nf * 16 + l15;
            bf[nf] = *(const half8*)(smem + 32768 + brow * 256 + g * 16);
        }
#pragma unroll
        for (int mf = 0; mf < 2; ++mf)
#pragma unroll
            for (int nf = 0; nf < 4; ++nf)
                acc[mf][nf] = mfma16(bf[nf], af[mf], acc[mf][nf]);   // row = l15 side
    }

    // ---- epilogue: per mf, 16 lane-local cells; 2-shuffle combine; direct write ----
#pragma unroll
    for (int mf = 0; mf < 2; ++mf) {
        const int la = labA[mf];
        float v[16];
        float m = NEG_LOW;
#pragma unroll
        for (int nf = 0; nf < 4; ++nf)
#pragma unroll
            for (int r = 0; r < 4; ++r) {
                float x = (lb[nf][r] != la) ? acc[mf][nf][r] : NEG_MASK;
                v[nf * 4 + r] = x;
                m = fmaxf(m, x);
            }
        float s0 = 0.f, s1 = 0.f;
#pragma unroll
        for (int k = 0; k < 8; ++k) {
            s0 += exp2fast(v[k]     - m);
            s1 += exp2fast(v[k + 8] - m);
        }
        float s = s0 + s1;
#pragma unroll
        for (int off = 16; off < 64; off <<= 1) {    // combine 4 l16-groups (same row)
            float m2 = __shfl_xor(m, off);
            float sx = __shfl_xor(s, off);
            float nm = fmaxf(m, m2);
            s = s * exp2fast(m - nm) + sx * exp2fast(m2 - nm);
            m = nm;
        }
        if (l < 16) {
            int row = R0 + wid * 32 + mf * 16 + l;
            pmx[(size_t)colblk * B_N + row] = m;
            ps [(size_t)colblk * B_N + row] = s;
        }
    }
}

// ---------------- classsum: 128-chunk combine + per-block class partials ----------------
__global__ void classsum_kernel(const float* __restrict__ pmx, const float* __restrict__ ps,
                                const int* __restrict__ labels,
                                float* __restrict__ partSum, unsigned int* __restrict__ partCnt)
{
    __shared__ float        csL[NCLS];
    __shared__ unsigned int ccL[NCLS];
    int t = threadIdx.x;
    if (t < NCLS) { csL[t] = 0.0f; ccL[t] = 0u; }
    __syncthreads();

    int j = blockIdx.x * blockDim.x + t;             // 64 blocks x 128 threads
    float m = -FLT_MAX;
#pragma unroll 16
    for (int c = 0; c < NCHK; ++c) m = fmaxf(m, pmx[(size_t)c * B_N + j]);
    float s = 0.0f;
#pragma unroll 16
    for (int c = 0; c < NCHK; ++c)
        s += ps[(size_t)c * B_N + j] * exp2fast(pmx[(size_t)c * B_N + j] - m);

    int lab = labels[j];
    atomicAdd(&csL[lab], s);
    atomicAdd(&ccL[lab], 1u);
    __syncthreads();
    if (t < NCLS) {
        partSum[blockIdx.x * NCLS + t] = csL[t];
        partCnt[blockIdx.x * NCLS + t] = ccL[t];
    }
}

__global__ void loss_kernel(const float* __restrict__ partSum,
                            const unsigned int* __restrict__ partCnt,
                            float* __restrict__ out)
{
    int c = threadIdx.x;  // 64 threads = 1 wave
    float cs = 0.0f;
    unsigned int cc = 0u;
    if (c < NCLS) {
#pragma unroll 8
        for (int b = 0; b < NPBLK; ++b) {
            cs += partSum[b * NCLS + c];
            cc += partCnt[b * NCLS + c];
        }
    }

    float tot = cs;
#pragma unroll
    for (int off = 1; off < 64; off <<= 1) tot += __shfl_xor(tot, off);

    float contrib = 0.0f;
    if (c < NCLS && cc > 0u) {
        float negc = (float)(B_N - (int)cc);
        float nds  = tot - cs;
        float x    = (negc > 0.0f) ? (nds / negc) : nds;
        float lp   = (cc >= 2u) ? (-logf(x + 1e-12f)) : 0.0f;
        contrib = (float)cc * lp;
    }
#pragma unroll
    for (int off = 1; off < 64; off <<= 1) contrib += __shfl_xor(contrib, off);
    if (c == 0) out[0] = -(contrib / (float)B_N);
}

extern "C" void kernel_launch(void* const* d_in, const int* in_sizes, int n_in,
                              void* d_out, int out_size, void* d_ws, size_t ws_size,
                              hipStream_t stream)
{
    const float* anchor = (const float*)d_in[0];
    const float* target = (const float*)d_in[1];
    const int*   labels = (const int*)d_in[2];
    float* out = (float*)d_out;

    const size_t PLANE = (size_t)B_N * D_K * sizeof(short);    // 2 MB
    const size_t PART  = (size_t)NCHK * B_N * sizeof(float);   // 4 MB
    char* ws = (char*)d_ws;
    short* aH = (short*)(ws);
    short* bH = (short*)(ws + PLANE);
    float* pmx = (float*)(ws + 2 * PLANE);
    float* ps  = (float*)(ws + 2 * PLANE + PART);
    char*  cls = ws + 2 * PLANE + 2 * PART;
    float*        partSum = (float*)cls;
    unsigned int* partCnt = (unsigned int*)(cls + NPBLK * NCLS * sizeof(float));

    prep_kernel<<<2 * (B_N * D_K / 8) / 256, 256, 0, stream>>>(anchor, target, aH, bH);
    rowstats_kernel<<<64 * NCHK, 256, 0, stream>>>(aH, bH, labels, pmx, ps);
    classsum_kernel<<<B_N / 128, 128, 0, stream>>>(pmx, ps, labels, partSum, partCnt);
    loss_kernel<<<1, 64, 0, stream>>>(partSum, partCnt, out);
}

// Round 15
// 51.269 us; speedup vs baseline: 1.4508x; 1.4508x over previous
//
#include <hip/hip_runtime.h>
#include <float.h>
#include <math.h>

typedef __attribute__((ext_vector_type(8))) short short8;
typedef __attribute__((ext_vector_type(8))) _Float16 half8;
typedef __attribute__((ext_vector_type(4))) float f32x4;

constexpr int B_N  = 8192;
constexpr int D_K  = 128;
constexpr int NCLS = 50;
constexpr int NCHK = 64;              // 128-col chunks
constexpr int NPBLK = 128;            // classsum partial blocks
constexpr float C_SCALE  = 28.853900817779268f;   // 20*log2(e), folded into A
constexpr float NEG_LOW  = -1.0e5f;
constexpr float NEG_MASK = -1.0e30f;

__device__ __forceinline__ float exp2fast(float x) { return __builtin_amdgcn_exp2f(x); }
__device__ __forceinline__ f32x4 mfma16(half8 a, half8 b, f32x4 c) {
    return __builtin_amdgcn_mfma_f32_16x16x32_f16(a, b, c, 0, 0, 0);
}
__device__ __forceinline__ void async_copy16(void* lds, const void* g) {
    __builtin_amdgcn_global_load_lds((const __attribute__((address_space(1))) unsigned int*)g,
                                     (__attribute__((address_space(3))) unsigned int*)lds,
                                     16, 0, 0);
}

// ---------------- prep: f32 -> f16 row-major; A pre-scaled by C_SCALE ----------------
__global__ void prep_kernel(const float* __restrict__ a, const float* __restrict__ b,
                            short* __restrict__ aH, short* __restrict__ bH)
{
    const int NPER = B_N * D_K / 8;
    int i = blockIdx.x * blockDim.x + threadIdx.x;
    const float* src = (i < NPER) ? a : b;
    short*       dst = (i < NPER) ? aH : bH;
    const float  sc  = (i < NPER) ? C_SCALE : 1.0f;
    int j = (i < NPER) ? i : i - NPER;
    const f32x4* sp = (const f32x4*)(src + (size_t)j * 8);
    f32x4 v0 = sp[0], v1 = sp[1];
    short8 h;
#pragma unroll
    for (int e = 0; e < 4; ++e) {
        h[e]     = __builtin_bit_cast(short, (_Float16)(sc * v0[e]));
        h[e + 4] = __builtin_bit_cast(short, (_Float16)(sc * v1[e]));
    }
    *(short8*)(dst + (size_t)j * 8) = h;
}

// ---------------- main: 128x128 tile, merge-free: wave = 32 rows x ALL 128 cols ----------------
// Swapped mfma(bf, af): our row = lane&15 side, our col = (lane>>4)*4 + reg side.
// Each wave's acc[2][8] covers its 32 rows x 128 cols -> row-complete in-wave,
// 2-shuffle combine, direct global write. ONE barrier per block.
__global__ __launch_bounds__(256)
void rowstats_kernel(const short* __restrict__ aH, const short* __restrict__ bH,
                     const int* __restrict__ labels,
                     float* __restrict__ pmx, float* __restrict__ ps)
{
    __shared__ __align__(16) char smem[65536];       // A 32KB | B 32KB

    const int bid    = blockIdx.x;
    const int colblk = bid & (NCHK - 1);             // same colblk -> same XCD (64%8==0)
    const int R0     = (bid >> 6) * 128;
    const int C0     = colblk * 128;

    const int tid = threadIdx.x;
    const int wid = tid >> 6, l = tid & 63;
    const int l15 = l & 15, l16 = l >> 4;

    // labels early (latency hides under staging)
    int labA[2];
#pragma unroll
    for (int mf = 0; mf < 2; ++mf)
        labA[mf] = labels[R0 + wid * 32 + mf * 16 + l15];
    int lb[8][4];
#pragma unroll
    for (int nf = 0; nf < 8; ++nf) {
        int4 t4 = *(const int4*)(labels + C0 + nf * 16 + l16 * 4);
        lb[nf][0] = t4.x; lb[nf][1] = t4.y; lb[nf][2] = t4.z; lb[nf][3] = t4.w;
    }

    // ---- stage A + B tiles (swizzled source -> linear LDS; verified scheme) ----
    {
        const int srow = tid >> 4, sp = tid & 15;
#pragma unroll
        for (int is = 0; is < 8; ++is) {
            int row = is * 16 + srow;
            int gs  = sp ^ (row & 7);
            char* da = smem + is * 4096 + (wid << 10);
            async_copy16(da,         aH + (size_t)(R0 + row) * D_K + gs * 8);
            async_copy16(da + 32768, bH + (size_t)(C0 + row) * D_K + gs * 8);
        }
    }
    __syncthreads();                                 // single barrier (drains vmcnt)

    // ---- K=128 sweep: 4 k-steps x 2 af x 8 bf, swapped operands ----
    f32x4 acc[2][8];
#pragma unroll
    for (int mf = 0; mf < 2; ++mf)
#pragma unroll
        for (int nf = 0; nf < 8; ++nf) acc[mf][nf] = f32x4{0.f, 0.f, 0.f, 0.f};

    const int swz = l15 & 7;
#pragma unroll
    for (int ks = 0; ks < 4; ++ks) {
        const int g = (ks * 4 + l16) ^ swz;
        half8 af[2], bf[8];
#pragma unroll
        for (int mf = 0; mf < 2; ++mf) {
            int row = wid * 32 + mf * 16 + l15;
            af[mf] = *(const half8*)(smem + row * 256 + g * 16);
        }
#pragma unroll
        for (int nf = 0; nf < 8; ++nf) {
            int brow = nf * 16 + l15;
            bf[nf] = *(const half8*)(smem + 32768 + brow * 256 + g * 16);
        }
#pragma unroll
        for (int mf = 0; mf < 2; ++mf)
#pragma unroll
            for (int nf = 0; nf < 8; ++nf)
                acc[mf][nf] = mfma16(bf[nf], af[mf], acc[mf][nf]);   // row = l15 side
    }

    // ---- epilogue: per mf, 32 lane-local cells; 2-shuffle combine; direct write ----
#pragma unroll
    for (int mf = 0; mf < 2; ++mf) {
        const int la = labA[mf];
        float v[32];
        float m = NEG_LOW;
#pragma unroll
        for (int nf = 0; nf < 8; ++nf)
#pragma unroll
            for (int r = 0; r < 4; ++r) {
                float x = (lb[nf][r] != la) ? acc[mf][nf][r] : NEG_MASK;
                v[nf * 4 + r] = x;
                m = fmaxf(m, x);
            }
        float s0 = 0.f, s1 = 0.f, s2 = 0.f, s3 = 0.f;
#pragma unroll
        for (int k = 0; k < 8; ++k) {
            s0 += exp2fast(v[k]      - m);
            s1 += exp2fast(v[k + 8]  - m);
            s2 += exp2fast(v[k + 16] - m);
            s3 += exp2fast(v[k + 24] - m);
        }
        float s = (s0 + s1) + (s2 + s3);
#pragma unroll
        for (int off = 16; off < 64; off <<= 1) {    // combine 4 l16-groups (same row)
            float m2 = __shfl_xor(m, off);
            float sx = __shfl_xor(s, off);
            float nm = fmaxf(m, m2);
            s = s * exp2fast(m - nm) + sx * exp2fast(m2 - nm);
            m = nm;
        }
        if (l < 16) {
            int row = R0 + wid * 32 + mf * 16 + l;
            pmx[(size_t)colblk * B_N + row] = m;
            ps [(size_t)colblk * B_N + row] = s;
        }
    }
}

// ---------------- classsum: 4 threads/row (16 chunks each) + per-block class partials ----------------
__global__ void classsum_kernel(const float* __restrict__ pmx, const float* __restrict__ ps,
                                const int* __restrict__ labels,
                                float* __restrict__ partSum, unsigned int* __restrict__ partCnt)
{
    __shared__ float        csL[NCLS];
    __shared__ unsigned int ccL[NCLS];
    int t = threadIdx.x;
    if (t < NCLS) { csL[t] = 0.0f; ccL[t] = 0u; }
    __syncthreads();

    int gi = blockIdx.x * blockDim.x + t;            // 128 blocks x 256 thr = 32768
    int j  = gi >> 2;                                // row
    int q  = gi & 3;                                 // quarter: 16 chunks
    float m = -FLT_MAX;
#pragma unroll 16
    for (int c = q * 16; c < q * 16 + 16; ++c)
        m = fmaxf(m, pmx[(size_t)c * B_N + j]);
#pragma unroll
    for (int off = 1; off < 4; off <<= 1) m = fmaxf(m, __shfl_xor(m, off));
    float s = 0.0f;
#pragma unroll 16
    for (int c = q * 16; c < q * 16 + 16; ++c)
        s += ps[(size_t)c * B_N + j] * exp2fast(pmx[(size_t)c * B_N + j] - m);
#pragma unroll
    for (int off = 1; off < 4; off <<= 1) s += __shfl_xor(s, off);

    if (q == 0) {
        int lab = labels[j];
        atomicAdd(&csL[lab], s);
        atomicAdd(&ccL[lab], 1u);
    }
    __syncthreads();
    if (t < NCLS) {
        partSum[blockIdx.x * NCLS + t] = csL[t];
        partCnt[blockIdx.x * NCLS + t] = ccL[t];
    }
}

__global__ void loss_kernel(const float* __restrict__ partSum,
                            const unsigned int* __restrict__ partCnt,
                            float* __restrict__ out)
{
    int c = threadIdx.x;  // 64 threads = 1 wave
    float cs = 0.0f;
    unsigned int cc = 0u;
    if (c < NCLS) {
#pragma unroll 8
        for (int b = 0; b < NPBLK; ++b) {
            cs += partSum[b * NCLS + c];
            cc += partCnt[b * NCLS + c];
        }
    }

    float tot = cs;
#pragma unroll
    for (int off = 1; off < 64; off <<= 1) tot += __shfl_xor(tot, off);

    float contrib = 0.0f;
    if (c < NCLS && cc > 0u) {
        float negc = (float)(B_N - (int)cc);
        float nds  = tot - cs;
        float x    = (negc > 0.0f) ? (nds / negc) : nds;
        float lp   = (cc >= 2u) ? (-logf(x + 1e-12f)) : 0.0f;
        contrib = (float)cc * lp;
    }
#pragma unroll
    for (int off = 1; off < 64; off <<= 1) contrib += __shfl_xor(contrib, off);
    if (c == 0) out[0] = -(contrib / (float)B_N);
}

extern "C" void kernel_launch(void* const* d_in, const int* in_sizes, int n_in,
                              void* d_out, int out_size, void* d_ws, size_t ws_size,
                              hipStream_t stream)
{
    const float* anchor = (const float*)d_in[0];
    const float* target = (const float*)d_in[1];
    const int*   labels = (const int*)d_in[2];
    float* out = (float*)d_out;

    const size_t PLANE = (size_t)B_N * D_K * sizeof(short);    // 2 MB
    const size_t PART  = (size_t)NCHK * B_N * sizeof(float);   // 2 MB
    char* ws = (char*)d_ws;
    short* aH = (short*)(ws);
    short* bH = (short*)(ws + PLANE);
    float* pmx = (float*)(ws + 2 * PLANE);
    float* ps  = (float*)(ws + 2 * PLANE + PART);
    char*  cls = ws + 2 * PLANE + 2 * PART;
    float*        partSum = (float*)cls;
    unsigned int* partCnt = (unsigned int*)(cls + NPBLK * NCLS * sizeof(float));

    prep_kernel<<<2 * (B_N * D_K / 8) / 256, 256, 0, stream>>>(anchor, target, aH, bH);
    rowstats_kernel<<<64 * NCHK, 256, 0, stream>>>(aH, bH, labels, pmx, ps);
    classsum_kernel<<<B_N * 4 / 256, 256, 0, stream>>>(pmx, ps, labels, partSum, partCnt);
    loss_kernel<<<1, 64, 0, stream>>>(partSum, partCnt, out);
}